// Round 3
// baseline (859.414 us; speedup 1.0000x reference)
//
#include <hip/hip_runtime.h>

typedef float f32x4 __attribute__((ext_vector_type(4)));
typedef __bf16 bf16x8 __attribute__((ext_vector_type(8)));

#define GAMMA_BOUND 3.814697265625e-06f      // 2^-18
#define PEDESTAL    1.4551915228366852e-11f  // 2^-36
#define BETA_BOUND  1.0000072759311327e-03f  // sqrt(1e-6 + 2^-36)
#define CH   128
#define XPAD 132   // padded row stride (floats) for the x stash

// One 16-row slab per block-iteration; grid-stride over slabs with
// cross-iteration register prefetch (issue-early / LDS-write-late).
// Wave w owns output column tiles {2w, 2w+1} (16 cols each).
// B (reparam'd g) fragments live permanently in VGPRs; A (x^2 hi/lo bf16)
// fragments + raw x rows staged in double-buffered LDS; ONE barrier per slab.
__global__ __launch_bounds__(256, 4) void gdn_main(
    const float* __restrict__ x, const float* __restrict__ beta,
    const float* __restrict__ gamma, float* __restrict__ out,
    int nrows, int nslabs)
{
  const int tid  = threadIdx.x;
  const int l    = tid & 63;   // lane
  const int w    = tid >> 6;   // wave 0..3
  const int lm16 = l & 15;
  const int lh   = l >> 4;     // 0..3

  // ---- one-time per block: build B fragments (reparameterized g) in regs.
  // B[k][i] = g[i][k]; lane mapping: col i = ct*16 + (l&15),
  // k = kt*32 + 8*(l>>4) + e   (e = vector element 0..7)
  bf16x8 bhi[2][4], blo[2][4];
  float breg[2];
#pragma unroll
  for (int c = 0; c < 2; ++c) {
    const int ct = 2 * w + c;
    const int i  = ct * 16 + lm16;
    {
      float bv = beta[i];
      bv = fmaxf(bv, BETA_BOUND);
      breg[c] = bv * bv - PEDESTAL;
    }
#pragma unroll
    for (int kt = 0; kt < 4; ++kt) {
      const int j0 = kt * 32 + 8 * lh;
      const f32x4 g0 = *(const f32x4*)(gamma + i * CH + j0);
      const f32x4 g1 = *(const f32x4*)(gamma + i * CH + j0 + 4);
      const float gv[8] = {g0.x, g0.y, g0.z, g0.w, g1.x, g1.y, g1.z, g1.w};
      bf16x8 h, lo;
#pragma unroll
      for (int e = 0; e < 8; ++e) {
        float g = fmaxf(gv[e], GAMMA_BOUND);
        g = g * g - PEDESTAL;
        const __bf16 hb = (__bf16)g;
        h[e]  = hb;
        lo[e] = (__bf16)(g - (float)hb);
      }
      bhi[c][kt] = h;
      blo[c][kt] = lo;
    }
  }

  // A-fragment staging: [buf][hi/lo][kt*64 + lane], 16 B each -> 16 KB
  __shared__ bf16x8 lds_a[2][2][256];
  // raw x stash for the epilogue (padded to kill bank conflicts) -> 16.5 KB
  __shared__ float  x_lds[2][16][XPAD];

  // producer mapping: thread t produces consumer fragment (kt=t>>6, lane=t&63)
  const int prow  = l & 15;                          // A row within slab
  const int pcol0 = (tid >> 6) * 32 + 8 * (l >> 4);  // first k of this lane's 8

  // ---- prologue: prefetch first slab into registers
  int s = blockIdx.x;
  f32x4 nv0 = {0.f, 0.f, 0.f, 0.f}, nv1 = {0.f, 0.f, 0.f, 0.f};
  {
    const int row = s * 16 + prow;
    if (row < nrows) {
      const float* xp = x + (size_t)row * CH + pcol0;
      nv0 = __builtin_nontemporal_load((const f32x4*)xp);
      nv1 = __builtin_nontemporal_load((const f32x4*)(xp + 4));
    }
  }

  int p = 0;
  for (; s < nslabs; s += gridDim.x) {
    const int rbase = s * 16;
    const f32x4 v0 = nv0, v1 = nv1;

    // ---- phase 1: stash raw x, square, bf16 hi/lo split, store A frags
    *(f32x4*)&x_lds[p][prow][pcol0]     = v0;
    *(f32x4*)&x_lds[p][prow][pcol0 + 4] = v1;
    {
      const float sq[8] = {v0.x * v0.x, v0.y * v0.y, v0.z * v0.z, v0.w * v0.w,
                           v1.x * v1.x, v1.y * v1.y, v1.z * v1.z, v1.w * v1.w};
      bf16x8 h, lo;
#pragma unroll
      for (int e = 0; e < 8; ++e) {
        const __bf16 hb = (__bf16)sq[e];
        h[e]  = hb;
        lo[e] = (__bf16)(sq[e] - (float)hb);
      }
      lds_a[p][0][tid] = h;
      lds_a[p][1][tid] = lo;
    }

    // ---- issue prefetch for the NEXT slab (stays in flight across the
    // barrier: plain reg-destined loads, not global_load_lds)
    nv0 = (f32x4){0.f, 0.f, 0.f, 0.f};
    nv1 = (f32x4){0.f, 0.f, 0.f, 0.f};
    {
      const int sn = s + gridDim.x;
      if (sn < nslabs) {
        const int row = sn * 16 + prow;
        if (row < nrows) {
          const float* xp = x + (size_t)row * CH + pcol0;
          nv0 = __builtin_nontemporal_load((const f32x4*)xp);
          nv1 = __builtin_nontemporal_load((const f32x4*)(xp + 4));
        }
      }
    }

    __syncthreads();   // the ONLY barrier per slab (double-buffered LDS)

    // ---- phase 2: 24 MFMAs/wave (2 col-tiles x 4 k-tiles x 3 split terms)
    f32x4 acc0 = {breg[0], breg[0], breg[0], breg[0]};
    f32x4 acc1 = {breg[1], breg[1], breg[1], breg[1]};
#pragma unroll
    for (int kt = 0; kt < 4; ++kt) {
      const bf16x8 ah = lds_a[p][0][kt * 64 + l];
      const bf16x8 al = lds_a[p][1][kt * 64 + l];
      acc0 = __builtin_amdgcn_mfma_f32_16x16x32_bf16(ah, bhi[0][kt], acc0, 0, 0, 0);
      acc1 = __builtin_amdgcn_mfma_f32_16x16x32_bf16(ah, bhi[1][kt], acc1, 0, 0, 0);
      acc0 = __builtin_amdgcn_mfma_f32_16x16x32_bf16(al, bhi[0][kt], acc0, 0, 0, 0);
      acc1 = __builtin_amdgcn_mfma_f32_16x16x32_bf16(al, bhi[1][kt], acc1, 0, 0, 0);
      acc0 = __builtin_amdgcn_mfma_f32_16x16x32_bf16(ah, blo[0][kt], acc0, 0, 0, 0);
      acc1 = __builtin_amdgcn_mfma_f32_16x16x32_bf16(ah, blo[1][kt], acc1, 0, 0, 0);
    }

    // ---- epilogue: out = x * refined_rsqrt(norm)
    // C/D layout (HW-verified): col = lane&15, row = (lane>>4)*4 + reg
#pragma unroll
    for (int c = 0; c < 2; ++c) {
      const int colg = (2 * w + c) * 16 + lm16;
      const f32x4 acc = c ? acc1 : acc0;
#pragma unroll
      for (int v = 0; v < 4; ++v) {
        const int rl = lh * 4 + v;          // local row in slab
        const int r  = rbase + rl;
        if (r < nrows) {
          const float n  = acc[v];
          float rr = rsqrtf(n);
          rr = rr * fmaf(-0.5f * n * rr, rr, 1.5f);   // one Newton step
          const float xv = x_lds[p][rl][colg];
          __builtin_nontemporal_store(xv * rr, out + (size_t)r * CH + colg);
        }
      }
    }
    p ^= 1;
  }
}

extern "C" void kernel_launch(void* const* d_in, const int* in_sizes, int n_in,
                              void* d_out, int out_size, void* d_ws, size_t ws_size,
                              hipStream_t stream) {
  const float* x     = (const float*)d_in[0];
  const float* beta  = (const float*)d_in[1];
  const float* gamma = (const float*)d_in[2];
  float* out = (float*)d_out;
  const int nrows  = in_sizes[0] / CH;
  const int nslabs = (nrows + 15) / 16;
  const int grid   = nslabs < 2048 ? nslabs : 2048;
  gdn_main<<<grid, 256, 0, stream>>>(x, beta, gamma, out, nrows, nslabs);
}